// Round 1
// baseline (440.301 us; speedup 1.0000x reference)
//
#include <hip/hip_runtime.h>
#include <hip/hip_bf16.h>

// Markov chain log-likelihood:
//   ll_b = log(init[x_{b,0}]) + sum_{t=1}^{len_b-1} log(trans[x_{b,t-1}, x_{b,t}])
//   out  = -logsumexp_b(ll_b)
//
// Inputs (setup_inputs order):
//   d_in[0] seqs   : int32 [B*S]
//   d_in[1] lengths: int32 [B]
//   d_in[2] init   : fp32  [NUM_STATES]
//   d_in[3] trans  : fp32  [NUM_STATES*NUM_STATES]   (400 MB, random gather)
// Output: fp32 scalar.

#define B_SEQ 64
#define S_LEN 4096
#define NSTATES 10000
#define P_BLOCKS 16          // partial blocks per sequence
#define BLOCK_T 256          // threads per block (P_BLOCKS*BLOCK_T = S_LEN)

// Kernel 1: per-transition gather + log, block reduction -> ws[b*P + p]
__global__ __launch_bounds__(BLOCK_T) void markov_partials(
    const int* __restrict__ seqs,
    const int* __restrict__ lengths,
    const float* __restrict__ trans,
    float* __restrict__ ws) {
    const int b = blockIdx.y;
    const int p = blockIdx.x;
    const int tid = threadIdx.x;

    const int len = lengths[b];
    // transition target index t in [1, S); t < len <= S implies in-bounds
    const int t = p * BLOCK_T + tid + 1;

    float v = 0.0f;
    if (t < len) {
        const int s0 = seqs[b * S_LEN + t - 1];
        const int s1 = seqs[b * S_LEN + t];
        const float pr = trans[(long long)s0 * NSTATES + s1];
        v = __logf(pr);
    }

    // wave (64-lane) shuffle reduction
    #pragma unroll
    for (int off = 32; off > 0; off >>= 1)
        v += __shfl_down(v, off, 64);

    // cross-wave reduction via LDS (4 waves of 64)
    __shared__ float wsum[BLOCK_T / 64];
    const int wave = tid >> 6;
    const int lane = tid & 63;
    if (lane == 0) wsum[wave] = v;
    __syncthreads();
    if (tid == 0) {
        float total = 0.0f;
        #pragma unroll
        for (int w = 0; w < BLOCK_T / 64; ++w) total += wsum[w];
        ws[b * P_BLOCKS + p] = total;
    }
}

// Kernel 2: one wave. Lane b: ll_b = log(init[x_{b,0}]) + sum of partials,
// then wave logsumexp, lane 0 writes -result.
__global__ __launch_bounds__(64) void markov_finalize(
    const int* __restrict__ seqs,
    const float* __restrict__ init,
    const float* __restrict__ ws,
    float* __restrict__ out) {
    const int b = threadIdx.x;   // 0..63

    float ll = __logf(init[seqs[b * S_LEN]]);
    #pragma unroll
    for (int p = 0; p < P_BLOCKS; ++p)
        ll += ws[b * P_BLOCKS + p];

    // wave max
    float m = ll;
    #pragma unroll
    for (int off = 32; off > 0; off >>= 1)
        m = fmaxf(m, __shfl_down(m, off, 64));
    m = __shfl(m, 0, 64);

    float e = __expf(ll - m);
    #pragma unroll
    for (int off = 32; off > 0; off >>= 1)
        e += __shfl_down(e, off, 64);

    if (b == 0)
        out[0] = -(m + __logf(e));
}

extern "C" void kernel_launch(void* const* d_in, const int* in_sizes, int n_in,
                              void* d_out, int out_size, void* d_ws, size_t ws_size,
                              hipStream_t stream) {
    const int* seqs      = (const int*)d_in[0];
    const int* lengths   = (const int*)d_in[1];
    const float* init    = (const float*)d_in[2];
    const float* trans   = (const float*)d_in[3];
    float* out           = (float*)d_out;
    float* ws            = (float*)d_ws;   // needs B_SEQ * P_BLOCKS floats = 4 KB

    dim3 grid(P_BLOCKS, B_SEQ);
    markov_partials<<<grid, BLOCK_T, 0, stream>>>(seqs, lengths, trans, ws);
    markov_finalize<<<1, 64, 0, stream>>>(seqs, init, ws, out);
}